// Round 12
// baseline (351.618 us; speedup 1.0000x reference)
//
#include <hip/hip_runtime.h>
#include <hip/hip_fp16.h>
#include <math.h>

#define NB 16
#define NA 720
#define ND 1024
#define NH 512
#define NW 512

#define TW 32      // tile width  (x)
#define TH 8       // tile height (y)
#define NBT 8      // batches per block
#define WREG 64    // padded window entries per (bank,phase,sg); real span<=36
#define SLANES 40  // staged lanes per DMA (covers window span 36; pad unread)

typedef __fp16 h2vec __attribute__((ext_vector_type(2)));

__device__ __forceinline__ uint32_t pkrtz_u32(float a, float b) {
    union { h2vec h; uint32_t u; } v;
    v.h = __builtin_amdgcn_cvt_pkrtz(a, b);   // one v_cvt_pkrtz_f16_f32
    return v.u;
}
__device__ __forceinline__ __half2 u32_to_h2(uint32_t u) {
    union { uint32_t u; __half2 h; } v; v.u = u; return v.h;
}
__device__ __forceinline__ uint32_t h2_to_u32(__half2 h) {
    union { __half2 h; uint32_t u; } v; v.h = h; return v.u;
}

// ---------------------------------------------------------------------------
// Kernel 0: per-(tile-position, angle) parameter table (1024 pos x 720 ang,
// entry (c, s, 511.5-base, bits(a*ND+base))) for the 32x8 tile grid + global
// FFT twiddle table (block 1024). t = px*c+py*s+511.5 in [150, 873] for all
// pixels/angles -> Gq row index a*ND+base+lane stays in [0, ND*NA) even with
// the padded staging read.
// ---------------------------------------------------------------------------
__global__ __launch_bounds__(768) void prep_kernel(float4* __restrict__ ptable,
                                                   float2* __restrict__ twg) {
    const int a = threadIdx.x;
    const int pos = blockIdx.x;
    if (pos == 1024) {
        float ang = (float)(-2.0 * M_PI / 1024.0) * (float)a;
        float s, c;
        sincosf(ang, &s, &c);
        twg[a] = make_float2(c, s);
        return;
    }
    if (a >= NA) return;
    const float step = (float)(M_PI / (double)NA);
    float s, c;
    sincosf((float)a * step, &s, &c);
    const int bx = pos & 15, by = pos >> 4;
    const float x0 = (float)(bx * TW) - 255.5f;
    const float x1 = x0 + (float)(TW - 1);
    const float y0 = (float)(by * TH) - 255.5f;
    // s >= 0 for angles in [0, pi): min over y at y0.
    const float tmin = 511.5f + fminf(x0 * c, x1 * c) + y0 * s;
    const int base = (int)floorf(tmin) - 1;
    ptable[pos * NA + a] = make_float4(c, s, 511.5f - (float)base,
                                       __int_as_float(a * ND + base));
}

// ---------------------------------------------------------------------------
// Kernel 1 (R12): ramp filter via in-LDS Stockham RADIX-4 FFT (fp32), XOR
// granule swizzle SZ, twiddles from the prep-built table. R12 cuts:
//  - Ns=1 stages PEELED in both directions (m=0 -> all twiddles are (1,0)):
//    saves 3 tw LDS reads + 3 cmuls per thread per direction.
//  - filter-multiply pass FOLDED into inverse stage 1 (scaling the inputs of
//    a linear transform == scaling its output): saves a full 1024-pt LDS
//    read-modify-write pass + 1 barrier. Bit-identical values.
// Pairs the two rows of a BATCH-PAIR at the SAME angle: z = x_2p + i*x_2p+1;
// real even filter -> Y = filt*Z; IFFT -> Re = batch 2p, Im = batch 2p+1.
// Main-path epilogue writes the GATHER-READY quad buffer
//   Gq[q][a][i] = (f_{2q}[i], df_{2q}[i], f_{2q+1}[i], df_{2q+1}[i])
// (16B entries; block p writes the (p&1) uint2 half). Fallback (gq==null):
// packed fp16-pair rows.
// ---------------------------------------------------------------------------
#define SZ(i) ((i) ^ (((i) >> 4) & 15))

__device__ __forceinline__ float2 cmul(float2 w, float2 v) {
    return make_float2(w.x * v.x - w.y * v.y, w.x * v.y + w.y * v.x);
}
__device__ __forceinline__ float2 cmulc(float2 w, float2 v) {  // conj(w)*v
    return make_float2(w.x * v.x + w.y * v.y, w.x * v.y - w.y * v.x);
}

__global__ __launch_bounds__(256) void filter_kernel(const float* __restrict__ sino,
                                                     const float* __restrict__ filt,
                                                     const float2* __restrict__ twg,
                                                     uint4* __restrict__ gq,
                                                     uint32_t* __restrict__ packed) {
    __shared__ float2 bufA[ND];
    __shared__ float2 bufB[ND];
    __shared__ float2 tw4[768];   // tw4[t] = exp(-2*pi*i*t/ND), t < 3N/4

    const int tid = threadIdx.x;
    const int a = blockIdx.x;       // angle
    const int p = blockIdx.y;       // batch pair
    const float* __restrict__ xa = sino + ((size_t)(2 * p) * NA + a) * ND;
    const float* __restrict__ xb = xa + (size_t)NA * ND;

    #pragma unroll
    for (int i = 0; i < ND; i += 256)
        bufA[SZ(i + tid)] = make_float2(xa[i + tid], xb[i + tid]);
    #pragma unroll
    for (int i = 0; i < 768; i += 256) {
        int m = i + tid;
        tw4[SZ(m)] = twg[m];
    }
    __syncthreads();

    float2* src = bufA;
    float2* dst = bufB;

    // ---- forward FFT: peeled Ns=1 (twiddles == 1) ----
    {
        const int j = tid;
        float2 u0 = src[SZ(j)];
        float2 u1 = src[SZ(j + 256)];
        float2 u2 = src[SZ(j + 512)];
        float2 u3 = src[SZ(j + 768)];
        float2 A  = make_float2(u0.x + u2.x, u0.y + u2.y);
        float2 Bb = make_float2(u0.x - u2.x, u0.y - u2.y);
        float2 C  = make_float2(u1.x + u3.x, u1.y + u3.y);
        float2 D  = make_float2(u1.x - u3.x, u1.y - u3.y);
        const int d = j << 2;
        dst[SZ(d)]     = make_float2(A.x + C.x, A.y + C.y);
        dst[SZ(d + 1)] = make_float2(Bb.x + D.y, Bb.y - D.x);   // -i*D
        dst[SZ(d + 2)] = make_float2(A.x - C.x, A.y - C.y);
        dst[SZ(d + 3)] = make_float2(Bb.x - D.y, Bb.y + D.x);   // +i*D
        __syncthreads();
        float2* tmp = src; src = dst; dst = tmp;
    }
    // ---- forward FFT: Ns = 4,16,64,256 ----
    for (int Ns = 4; Ns < ND; Ns <<= 2) {
        const int j = tid;
        const int m = j & (Ns - 1);
        const int tstep = (ND / 4) / Ns;
        float2 u0 = src[SZ(j)];
        float2 x1 = src[SZ(j + 256)];
        float2 x2 = src[SZ(j + 512)];
        float2 x3 = src[SZ(j + 768)];
        float2 w1 = tw4[SZ(m * tstep)];
        float2 w2 = tw4[SZ(2 * m * tstep)];
        float2 w3 = tw4[SZ(3 * m * tstep)];
        float2 u1 = cmul(w1, x1), u2 = cmul(w2, x2), u3 = cmul(w3, x3);
        float2 A  = make_float2(u0.x + u2.x, u0.y + u2.y);
        float2 Bb = make_float2(u0.x - u2.x, u0.y - u2.y);
        float2 C  = make_float2(u1.x + u3.x, u1.y + u3.y);
        float2 D  = make_float2(u1.x - u3.x, u1.y - u3.y);
        const int d = ((j & ~(Ns - 1)) << 2) + m;
        dst[SZ(d)]          = make_float2(A.x + C.x, A.y + C.y);
        dst[SZ(d + Ns)]     = make_float2(Bb.x + D.y, Bb.y - D.x);   // -i*D
        dst[SZ(d + 2 * Ns)] = make_float2(A.x - C.x, A.y - C.y);
        dst[SZ(d + 3 * Ns)] = make_float2(Bb.x - D.y, Bb.y + D.x);   // +i*D
        __syncthreads();
        float2* tmp = src; src = dst; dst = tmp;
    }

    // ---- inverse FFT: peeled Ns=1 with the filter multiply FOLDED in ----
    const float SCALE = 1.0f / (float)ND;
    {
        const int j = tid;
        const float f0 = filt[j]       * SCALE;
        const float f1 = filt[j + 256] * SCALE;
        const float f2 = filt[j + 512] * SCALE;
        const float f3 = filt[j + 768] * SCALE;
        float2 u0 = src[SZ(j)];       u0.x *= f0; u0.y *= f0;
        float2 u1 = src[SZ(j + 256)]; u1.x *= f1; u1.y *= f1;
        float2 u2 = src[SZ(j + 512)]; u2.x *= f2; u2.y *= f2;
        float2 u3 = src[SZ(j + 768)]; u3.x *= f3; u3.y *= f3;
        float2 A  = make_float2(u0.x + u2.x, u0.y + u2.y);
        float2 Bb = make_float2(u0.x - u2.x, u0.y - u2.y);
        float2 C  = make_float2(u1.x + u3.x, u1.y + u3.y);
        float2 D  = make_float2(u1.x - u3.x, u1.y - u3.y);
        const int d = j << 2;
        dst[SZ(d)]     = make_float2(A.x + C.x, A.y + C.y);
        dst[SZ(d + 1)] = make_float2(Bb.x - D.y, Bb.y + D.x);   // +i*D
        dst[SZ(d + 2)] = make_float2(A.x - C.x, A.y - C.y);
        dst[SZ(d + 3)] = make_float2(Bb.x + D.y, Bb.y - D.x);   // -i*D
        __syncthreads();
        float2* tmp = src; src = dst; dst = tmp;
    }
    // ---- inverse FFT: Ns = 4,16,64,256 (conjugated twiddles) ----
    for (int Ns = 4; Ns < ND; Ns <<= 2) {
        const int j = tid;
        const int m = j & (Ns - 1);
        const int tstep = (ND / 4) / Ns;
        float2 u0 = src[SZ(j)];
        float2 x1 = src[SZ(j + 256)];
        float2 x2 = src[SZ(j + 512)];
        float2 x3 = src[SZ(j + 768)];
        float2 w1 = tw4[SZ(m * tstep)];
        float2 w2 = tw4[SZ(2 * m * tstep)];
        float2 w3 = tw4[SZ(3 * m * tstep)];
        float2 u1 = cmulc(w1, x1), u2 = cmulc(w2, x2), u3 = cmulc(w3, x3);
        float2 A  = make_float2(u0.x + u2.x, u0.y + u2.y);
        float2 Bb = make_float2(u0.x - u2.x, u0.y - u2.y);
        float2 C  = make_float2(u1.x + u3.x, u1.y + u3.y);
        float2 D  = make_float2(u1.x - u3.x, u1.y - u3.y);
        const int d = ((j & ~(Ns - 1)) << 2) + m;
        dst[SZ(d)]          = make_float2(A.x + C.x, A.y + C.y);
        dst[SZ(d + Ns)]     = make_float2(Bb.x - D.y, Bb.y + D.x);   // +i*D
        dst[SZ(d + 2 * Ns)] = make_float2(A.x - C.x, A.y - C.y);
        dst[SZ(d + 3 * Ns)] = make_float2(Bb.x + D.y, Bb.y - D.x);   // -i*D
        __syncthreads();
        float2* tmp = src; src = dst; dst = tmp;
    }

    if (gq != nullptr) {
        // gather-ready quad entries: block p fills the (p&1) half of quad p>>1
        char* gb = (char*)(gq + ((size_t)(p >> 1) * NA + a) * ND) + (p & 1) * 8;
        #pragma unroll
        for (int i = 0; i < ND; i += 256) {
            const int idx = i + tid;
            float2 v = src[SZ(idx)];
            uint32_t u = pkrtz_u32(v.x, v.y);
            float2 vn = src[SZ(min(idx + 1, ND - 1))];
            uint32_t un = pkrtz_u32(vn.x, vn.y);
            *(uint2*)(gb + (size_t)idx * 16) = make_uint2(
                u, h2_to_u32(__hsub2(u32_to_h2(un), u32_to_h2(u))));
        }
    } else {
        uint32_t* __restrict__ yo = packed + ((size_t)(2 * p) * NA + a) * ND;
        #pragma unroll
        for (int i = 0; i < ND; i += 256) {
            float2 v = src[SZ(i + tid)];
            yo[i + tid] = pkrtz_u32(v.x, v.y);
        }
    }
}

// ---------------------------------------------------------------------------
// Kernel 2 (frozen at R11 = best measured, 263us): DMA-staged backprojection
// with lane-masked DMA. At the structural LDS-gather floor: 2 ds_read_b128
// per thread-angle (32B fp16 lerp data / 16B max read width, irreducible),
// 46,080 wave-ops/CU x ~13.7 cyc effective = 263us. Conflicts = 0,
// occupancy 66% (8 blocks/CU; going below hurts — R10), write-port traffic
// non-additive (R11 mask null). Do not touch.
// ---------------------------------------------------------------------------
__global__ __launch_bounds__(256, 8) void backproj_kernel(const uint4* __restrict__ gq,
                                                          const float4* __restrict__ ptable,
                                                          float* __restrict__ img) {
    // win[bank][phase][sg][entry]: 2*4*2*64*16B = 16 KB -> 8 blocks/CU
    __shared__ __align__(16) uint4 win[2][4][2][WREG];

    const int tid = threadIdx.x;
    const int bx = blockIdx.x, by = blockIdx.y, bz = blockIdx.z;

    const float4* __restrict__ pt = ptable + (size_t)((by << 4) + bx) * NA;

    // lane map: wave = 8x x 8y patch; 4 waves tile x
    const int lane = tid & 63;
    const int wid  = tid >> 6;
    const int tx   = (wid << 3) + (lane & 7);
    const int ty   = lane >> 3;                       // 0..7
    const float px  = (float)(bx * TW + tx) - 255.5f;
    const float pyf = (float)(by * TH + ty) - 255.5f;

    // staging sources: quad rows 2bz (sg0: batches 8bz+0..3) and 2bz+1
    // (sg1: batches 8bz+4..7); per-lane global address, linear LDS dest.
    const uint4* __restrict__ q0 = gq + (size_t)(2 * bz) * NA * ND + lane;
    const uint4* __restrict__ q1 = q0 + (size_t)NA * ND;

    float accf[8];
    __half2 hacc01 = u32_to_h2(0u), hacc23 = u32_to_h2(0u),
            hacc45 = u32_to_h2(0u), hacc67 = u32_to_h2(0u);
    #pragma unroll
    for (int b = 0; b < 8; b++) accf[b] = 0.0f;

    auto gld = [](const uint4* g, uint4* l) {
        __builtin_amdgcn_global_load_lds(
            (const __attribute__((address_space(1))) void*)g,
            (__attribute__((address_space(3))) void*)l, 16, 0, 0);
    };
    // stage 4 angles (a..a+3, clamped) into one bank; wave 0, lanes < SLANES
    auto stage4 = [&](int a, uint4* bank) {
        if (lane < SLANES) {
            #pragma unroll
            for (int j = 0; j < 4; j++) {
                const int off = __float_as_int(pt[min(a + j, NA - 1)].w);
                gld(q0 + off, bank + j * (2 * WREG));
                gld(q1 + off, bank + j * (2 * WREG) + WREG);
            }
        }
    };
    auto consume = [&](float4 P, const uint4* wb, int ph) {
        const float t = fmaf(px, P.x, fmaf(pyf, P.y, P.z));
        const int i0 = (int)t;                    // t > 0 -> trunc == floor
#if __has_builtin(__builtin_amdgcn_fractf)
        float w = __builtin_amdgcn_fractf(t);
#else
        float w = t - (float)i0;
#endif
        __half2 wh2 = u32_to_h2(pkrtz_u32(w, w));     // one pkrtz
        const uint4 qA = wb[ph * 2 * WREG + i0];          // ds_read_b128
        const uint4 qB = wb[ph * 2 * WREG + WREG + i0];   // ds_read_b128
        hacc01 = __hfma2(wh2, u32_to_h2(qA.y), __hadd2(hacc01, u32_to_h2(qA.x)));
        hacc23 = __hfma2(wh2, u32_to_h2(qA.w), __hadd2(hacc23, u32_to_h2(qA.z)));
        hacc45 = __hfma2(wh2, u32_to_h2(qB.y), __hadd2(hacc45, u32_to_h2(qB.x)));
        hacc67 = __hfma2(wh2, u32_to_h2(qB.w), __hadd2(hacc67, u32_to_h2(qB.z)));
    };

    // prologue: stage angles 0..3 into bank0; drain; publish
    if (wid == 0) {
        stage4(0, &win[0][0][0][0]);
        asm volatile("s_waitcnt vmcnt(0)" ::: "memory");
    }
    __builtin_amdgcn_s_barrier();

    #pragma unroll 1
    for (int r = 0; r < NA / 4; ++r) {
        const int a = 4 * r;
        const uint4* wb = &win[r & 1][0][0][0];
        if (wid == 0)
            stage4(a + 4, &win[(r + 1) & 1][0][0][0]);
        const float4 P0 = pt[a],     P1 = pt[a + 1];
        const float4 P2 = pt[a + 2], P3 = pt[a + 3];
        consume(P0, wb, 0);
        consume(P1, wb, 1);
        consume(P2, wb, 2);
        consume(P3, wb, 3);

        // flush fp16 group accumulators into fp32 every 4 rounds (16 angles)
        if ((r & 3) == 3) {
            float2 v01 = __half22float2(hacc01);
            float2 v23 = __half22float2(hacc23);
            float2 v45 = __half22float2(hacc45);
            float2 v67 = __half22float2(hacc67);
            accf[0] += v01.x; accf[1] += v01.y;
            accf[2] += v23.x; accf[3] += v23.y;
            accf[4] += v45.x; accf[5] += v45.y;
            accf[6] += v67.x; accf[7] += v67.y;
            hacc01 = u32_to_h2(0u); hacc23 = u32_to_h2(0u);
            hacc45 = u32_to_h2(0u); hacc67 = u32_to_h2(0u);
        }
        if (wid == 0)
            asm volatile("s_waitcnt vmcnt(0)" ::: "memory");
        asm volatile("s_waitcnt lgkmcnt(0)" ::: "memory");
        __builtin_amdgcn_s_barrier();
    }

    const float SCALE = (float)(M_PI / (double)NA);
    const size_t bstride = (size_t)NH * NW;
    size_t o0 = (((size_t)(bz * NBT) * NH) + (by * TH + ty)) * NW + (bx * TW + tx);
    #pragma unroll
    for (int b = 0; b < 8; b++)
        img[o0 + (size_t)b * bstride] = accf[b] * SCALE;
}

// ---------------------------------------------------------------------------
// Fallback backprojection (register staging from packed rows) — used when
// the workspace cannot hold Gq + ptable.
// ---------------------------------------------------------------------------
#define WINN 36
__global__ __launch_bounds__(256, 8) void backproj_fb(const uint32_t* __restrict__ packed,
                                                      const float4* __restrict__ ptable,
                                                      float* __restrict__ img) {
    __shared__ __align__(16) uint4 win[2][8][WINN];

    const int tid = threadIdx.x;
    const int bx = blockIdx.x, by = blockIdx.y, bz = blockIdx.z;

    const float4* __restrict__ pt = ptable + (size_t)((by << 4) + bx) * NA;

    const bool stg = tid < 2 * WINN;
    const int sg   = (tid >= WINN) ? 1 : 0;
    const int si   = tid - sg * WINN;
    const uint32_t* __restrict__ sbA =
        packed + (size_t)(2 * (4 * bz + 2 * sg)) * NA * ND + si;
    const uint32_t* __restrict__ sbB = sbA + (size_t)2 * NA * ND;
    uint4* const wptr = &win[sg][0][si];

    const int lane = tid & 63;
    const int wid  = tid >> 6;
    const int tx   = (wid << 3) + (lane & 7);
    const int ty   = lane >> 3;
    const float px  = (float)(bx * TW + tx) - 255.5f;
    const float pyf = (float)(by * TH + ty) - 255.5f;

    float accf[8];
    __half2 hacc01 = u32_to_h2(0u), hacc23 = u32_to_h2(0u),
            hacc45 = u32_to_h2(0u), hacc67 = u32_to_h2(0u);
    #pragma unroll
    for (int b = 0; b < 8; b++) accf[b] = 0.0f;

    auto bar = []() {
        asm volatile("s_waitcnt lgkmcnt(0)" ::: "memory");
        __builtin_amdgcn_s_barrier();
    };
    auto stage_load = [&](float4 P, uint2& wA, uint2& wB) {
        const int off = __float_as_int(P.w);
        wA = make_uint2(sbA[off], sbA[off + 1]);
        wB = make_uint2(sbB[off], sbB[off + 1]);
    };
    auto stage_write = [&](int ph, uint2 wA, uint2 wB) {
        wptr[ph * WINN] = make_uint4(
            wA.x, h2_to_u32(__hsub2(u32_to_h2(wA.y), u32_to_h2(wA.x))),
            wB.x, h2_to_u32(__hsub2(u32_to_h2(wB.y), u32_to_h2(wB.x))));
    };
    auto consume = [&](float4 P, int ph) {
        const float t = fmaf(px, P.x, fmaf(pyf, P.y, P.z));
        const int i0 = (int)t;
#if __has_builtin(__builtin_amdgcn_fractf)
        float w = __builtin_amdgcn_fractf(t);
#else
        float w = t - (float)i0;
#endif
        __half2 wh2 = u32_to_h2(pkrtz_u32(w, w));
        const uint4 qA = win[0][ph][i0];
        const uint4 qB = win[1][ph][i0];
        hacc01 = __hfma2(wh2, u32_to_h2(qA.y), __hadd2(hacc01, u32_to_h2(qA.x)));
        hacc23 = __hfma2(wh2, u32_to_h2(qA.w), __hadd2(hacc23, u32_to_h2(qA.z)));
        hacc45 = __hfma2(wh2, u32_to_h2(qB.y), __hadd2(hacc45, u32_to_h2(qB.x)));
        hacc67 = __hfma2(wh2, u32_to_h2(qB.w), __hadd2(hacc67, u32_to_h2(qB.z)));
    };

    uint2 h0A = make_uint2(0, 0), h0B = make_uint2(0, 0);
    uint2 h1A = make_uint2(0, 0), h1B = make_uint2(0, 0);
    uint2 h2A = make_uint2(0, 0), h2B = make_uint2(0, 0);
    uint2 h3A = make_uint2(0, 0), h3B = make_uint2(0, 0);

    if (stg) {
        uint2 wA, wB;
        stage_load(pt[0], wA, wB);  stage_write(0, wA, wB);
        stage_load(pt[1], wA, wB);  stage_write(1, wA, wB);
        stage_load(pt[2], wA, wB);  stage_write(2, wA, wB);
        stage_load(pt[3], wA, wB);  stage_write(3, wA, wB);
        stage_load(pt[4], h0A, h0B);
        stage_load(pt[5], h1A, h1B);
        stage_load(pt[6], h2A, h2B);
        stage_load(pt[7], h3A, h3B);
    }
    bar();

    #pragma unroll 1
    for (int r = 0; r < NA / 4; ++r) {
        const int a = 4 * r;
        const int cb = (r & 1) * 4;
        const int ob = cb ^ 4;
        const float4 P0 = pt[a],     P1 = pt[a + 1];
        const float4 P2 = pt[a + 2], P3 = pt[a + 3];

        if (stg) {
            stage_write(ob + 0, h0A, h0B);
            stage_write(ob + 1, h1A, h1B);
            stage_write(ob + 2, h2A, h2B);
            stage_write(ob + 3, h3A, h3B);
            stage_load(pt[min(a + 8,  NA - 1)], h0A, h0B);
            stage_load(pt[min(a + 9,  NA - 1)], h1A, h1B);
            stage_load(pt[min(a + 10, NA - 1)], h2A, h2B);
            stage_load(pt[min(a + 11, NA - 1)], h3A, h3B);
        }
        consume(P0, cb + 0);
        consume(P1, cb + 1);
        consume(P2, cb + 2);
        consume(P3, cb + 3);

        if ((r & 3) == 3) {
            float2 v01 = __half22float2(hacc01);
            float2 v23 = __half22float2(hacc23);
            float2 v45 = __half22float2(hacc45);
            float2 v67 = __half22float2(hacc67);
            accf[0] += v01.x; accf[1] += v01.y;
            accf[2] += v23.x; accf[3] += v23.y;
            accf[4] += v45.x; accf[5] += v45.y;
            accf[6] += v67.x; accf[7] += v67.y;
            hacc01 = u32_to_h2(0u); hacc23 = u32_to_h2(0u);
            hacc45 = u32_to_h2(0u); hacc67 = u32_to_h2(0u);
        }
        bar();
    }

    const float SCALE = (float)(M_PI / (double)NA);
    const size_t bstride = (size_t)NH * NW;
    size_t o0 = (((size_t)(bz * NBT) * NH) + (by * TH + ty)) * NW + (bx * TW + tx);
    #pragma unroll
    for (int b = 0; b < 8; b++)
        img[o0 + (size_t)b * bstride] = accf[b] * SCALE;
}

// ---------------------------------------------------------------------------
extern "C" void kernel_launch(void* const* d_in, const int* in_sizes, int n_in,
                              void* d_out, int out_size, void* d_ws, size_t ws_size,
                              hipStream_t stream) {
    const float* sino = (const float*)d_in[0];
    const float* filt = (const float*)d_in[1];
    float* out = (float*)d_out;

    const size_t gq_bytes   = (size_t)4 * NA * ND * sizeof(uint4);       // 47.2 MB
    const size_t ptab_bytes = (size_t)1024 * NA * sizeof(float4);        // 11.8 MB
    const size_t twg_bytes  = (size_t)768 * sizeof(float2);              //  6 KB

    if (ws_size >= gq_bytes + ptab_bytes + twg_bytes) {
        uint4*  gq     = (uint4*)d_ws;
        float4* ptable = (float4*)((char*)d_ws + gq_bytes);
        float2* twg    = (float2*)((char*)d_ws + gq_bytes + ptab_bytes);
        prep_kernel<<<dim3(1025), dim3(768), 0, stream>>>(ptable, twg);
        filter_kernel<<<dim3(NA, NB / 2), dim3(256), 0, stream>>>(sino, filt, twg, gq, nullptr);
        backproj_kernel<<<dim3(NW / TW, NH / TH, NB / NBT), dim3(256), 0, stream>>>(gq, ptable, out);
    } else {
        // fallback: pack fp16 rows in-place into the input (block-local
        // writes); ptable + twiddles in d_ws; register-staging backproj.
        uint32_t* packed = (uint32_t*)d_in[0];
        float4* ptable   = (float4*)d_ws;
        float2* twg      = (float2*)((char*)d_ws + ptab_bytes);
        prep_kernel<<<dim3(1025), dim3(768), 0, stream>>>(ptable, twg);
        filter_kernel<<<dim3(NA, NB / 2), dim3(256), 0, stream>>>(sino, filt, twg, nullptr, packed);
        backproj_fb<<<dim3(NW / TW, NH / TH, NB / NBT), dim3(256), 0, stream>>>(packed, ptable, out);
    }
}

// Round 13
// 332.267 us; speedup vs baseline: 1.0582x; 1.0582x over previous
//
#include <hip/hip_runtime.h>
#include <hip/hip_fp16.h>
#include <math.h>

#define NB 16
#define NA 720
#define ND 1024
#define NH 512
#define NW 512

#define TW 32      // tile width  (x)
#define TH 8       // tile height (y)
#define NBT 8      // batches per block
#define WREG 64    // padded window entries per (bank,phase,sg); real span<=36
#define SLANES 40  // staged lanes per DMA (covers window span 36; pad unread)

typedef __fp16 h2vec __attribute__((ext_vector_type(2)));

__device__ __forceinline__ uint32_t pkrtz_u32(float a, float b) {
    union { h2vec h; uint32_t u; } v;
    v.h = __builtin_amdgcn_cvt_pkrtz(a, b);   // one v_cvt_pkrtz_f16_f32
    return v.u;
}
__device__ __forceinline__ __half2 u32_to_h2(uint32_t u) {
    union { uint32_t u; __half2 h; } v; v.u = u; return v.h;
}
__device__ __forceinline__ uint32_t h2_to_u32(__half2 h) {
    union { __half2 h; uint32_t u; } v; v.h = h; return v.u;
}

// ---------------------------------------------------------------------------
// Kernel 0: per-(tile-position, angle) parameter table (1024 pos x 720 ang,
// entry (c, s, 511.5-base, bits(a*ND+base))) for the 32x8 tile grid + global
// FFT twiddle table (block 1024). t = px*c+py*s+511.5 in [150, 873] for all
// pixels/angles -> Gq row index a*ND+base+lane stays in [0, ND*NA) even with
// the padded staging read.
// ---------------------------------------------------------------------------
__global__ __launch_bounds__(768) void prep_kernel(float4* __restrict__ ptable,
                                                   float2* __restrict__ twg) {
    const int a = threadIdx.x;
    const int pos = blockIdx.x;
    if (pos == 1024) {
        float ang = (float)(-2.0 * M_PI / 1024.0) * (float)a;
        float s, c;
        sincosf(ang, &s, &c);
        twg[a] = make_float2(c, s);
        return;
    }
    if (a >= NA) return;
    const float step = (float)(M_PI / (double)NA);
    float s, c;
    sincosf((float)a * step, &s, &c);
    const int bx = pos & 15, by = pos >> 4;
    const float x0 = (float)(bx * TW) - 255.5f;
    const float x1 = x0 + (float)(TW - 1);
    const float y0 = (float)(by * TH) - 255.5f;
    // s >= 0 for angles in [0, pi): min over y at y0.
    const float tmin = 511.5f + fminf(x0 * c, x1 * c) + y0 * s;
    const int base = (int)floorf(tmin) - 1;
    ptable[pos * NA + a] = make_float4(c, s, 511.5f - (float)base,
                                       __int_as_float(a * ND + base));
}

// ---------------------------------------------------------------------------
// Kernel 1 (R13 = R11 revert): ramp filter via in-LDS Stockham RADIX-4 FFT
// (fp32), 5 uniform passes per direction, XOR granule swizzle SZ, twiddles
// from the prep-built table. R12's peel/fold restructure regressed the total
// (+19us vs predicted -6..-10) — reverted to the best-measured form.
// Pairs the two rows of a BATCH-PAIR at the SAME angle: z = x_2p + i*x_2p+1;
// real even filter -> Y = filt*Z; IFFT -> Re = batch 2p, Im = batch 2p+1.
// Main-path epilogue writes the GATHER-READY quad buffer
//   Gq[q][a][i] = (f_{2q}[i], df_{2q}[i], f_{2q+1}[i], df_{2q+1}[i])
// (16B entries; block p writes the (p&1) uint2 half). Fallback (gq==null):
// packed fp16-pair rows.
// ---------------------------------------------------------------------------
#define SZ(i) ((i) ^ (((i) >> 4) & 15))

__device__ __forceinline__ float2 cmul(float2 w, float2 v) {
    return make_float2(w.x * v.x - w.y * v.y, w.x * v.y + w.y * v.x);
}
__device__ __forceinline__ float2 cmulc(float2 w, float2 v) {  // conj(w)*v
    return make_float2(w.x * v.x + w.y * v.y, w.x * v.y - w.y * v.x);
}

__global__ __launch_bounds__(256) void filter_kernel(const float* __restrict__ sino,
                                                     const float* __restrict__ filt,
                                                     const float2* __restrict__ twg,
                                                     uint4* __restrict__ gq,
                                                     uint32_t* __restrict__ packed) {
    __shared__ float2 bufA[ND];
    __shared__ float2 bufB[ND];
    __shared__ float2 tw4[768];   // tw4[t] = exp(-2*pi*i*t/ND), t < 3N/4

    const int tid = threadIdx.x;
    const int a = blockIdx.x;       // angle
    const int p = blockIdx.y;       // batch pair
    const float* __restrict__ xa = sino + ((size_t)(2 * p) * NA + a) * ND;
    const float* __restrict__ xb = xa + (size_t)NA * ND;

    #pragma unroll
    for (int i = 0; i < ND; i += 256)
        bufA[SZ(i + tid)] = make_float2(xa[i + tid], xb[i + tid]);
    #pragma unroll
    for (int i = 0; i < 768; i += 256) {
        int m = i + tid;
        tw4[SZ(m)] = twg[m];
    }
    __syncthreads();

    float2* src = bufA;
    float2* dst = bufB;

    // forward FFT: Stockham radix-4, Ns = 1,4,16,64,256
    for (int Ns = 1; Ns < ND; Ns <<= 2) {
        const int j = tid;
        const int m = j & (Ns - 1);
        const int tstep = (ND / 4) / Ns;
        float2 u0 = src[SZ(j)];
        float2 x1 = src[SZ(j + 256)];
        float2 x2 = src[SZ(j + 512)];
        float2 x3 = src[SZ(j + 768)];
        float2 w1 = tw4[SZ(m * tstep)];
        float2 w2 = tw4[SZ(2 * m * tstep)];
        float2 w3 = tw4[SZ(3 * m * tstep)];
        float2 u1 = cmul(w1, x1), u2 = cmul(w2, x2), u3 = cmul(w3, x3);
        float2 A  = make_float2(u0.x + u2.x, u0.y + u2.y);
        float2 Bb = make_float2(u0.x - u2.x, u0.y - u2.y);
        float2 C  = make_float2(u1.x + u3.x, u1.y + u3.y);
        float2 D  = make_float2(u1.x - u3.x, u1.y - u3.y);
        const int d = ((j & ~(Ns - 1)) << 2) + m;
        dst[SZ(d)]          = make_float2(A.x + C.x, A.y + C.y);
        dst[SZ(d + Ns)]     = make_float2(Bb.x + D.y, Bb.y - D.x);   // -i*D
        dst[SZ(d + 2 * Ns)] = make_float2(A.x - C.x, A.y - C.y);
        dst[SZ(d + 3 * Ns)] = make_float2(Bb.x - D.y, Bb.y + D.x);   // +i*D
        __syncthreads();
        float2* tmp = src; src = dst; dst = tmp;
    }

    // multiply by real filter, with 1/ND folded in
    const float SCALE = 1.0f / (float)ND;
    #pragma unroll
    for (int i = 0; i < ND; i += 256) {
        float f = filt[i + tid] * SCALE;
        src[SZ(i + tid)].x *= f;
        src[SZ(i + tid)].y *= f;
    }
    __syncthreads();

    // inverse FFT: conjugated twiddles, y1/y3 swapped (+i/-i)
    for (int Ns = 1; Ns < ND; Ns <<= 2) {
        const int j = tid;
        const int m = j & (Ns - 1);
        const int tstep = (ND / 4) / Ns;
        float2 u0 = src[SZ(j)];
        float2 x1 = src[SZ(j + 256)];
        float2 x2 = src[SZ(j + 512)];
        float2 x3 = src[SZ(j + 768)];
        float2 w1 = tw4[SZ(m * tstep)];
        float2 w2 = tw4[SZ(2 * m * tstep)];
        float2 w3 = tw4[SZ(3 * m * tstep)];
        float2 u1 = cmulc(w1, x1), u2 = cmulc(w2, x2), u3 = cmulc(w3, x3);
        float2 A  = make_float2(u0.x + u2.x, u0.y + u2.y);
        float2 Bb = make_float2(u0.x - u2.x, u0.y - u2.y);
        float2 C  = make_float2(u1.x + u3.x, u1.y + u3.y);
        float2 D  = make_float2(u1.x - u3.x, u1.y - u3.y);
        const int d = ((j & ~(Ns - 1)) << 2) + m;
        dst[SZ(d)]          = make_float2(A.x + C.x, A.y + C.y);
        dst[SZ(d + Ns)]     = make_float2(Bb.x - D.y, Bb.y + D.x);   // +i*D
        dst[SZ(d + 2 * Ns)] = make_float2(A.x - C.x, A.y - C.y);
        dst[SZ(d + 3 * Ns)] = make_float2(Bb.x + D.y, Bb.y - D.x);   // -i*D
        __syncthreads();
        float2* tmp = src; src = dst; dst = tmp;
    }

    if (gq != nullptr) {
        // gather-ready quad entries: block p fills the (p&1) half of quad p>>1
        char* gb = (char*)(gq + ((size_t)(p >> 1) * NA + a) * ND) + (p & 1) * 8;
        #pragma unroll
        for (int i = 0; i < ND; i += 256) {
            const int idx = i + tid;
            float2 v = src[SZ(idx)];
            uint32_t u = pkrtz_u32(v.x, v.y);
            float2 vn = src[SZ(min(idx + 1, ND - 1))];
            uint32_t un = pkrtz_u32(vn.x, vn.y);
            *(uint2*)(gb + (size_t)idx * 16) = make_uint2(
                u, h2_to_u32(__hsub2(u32_to_h2(un), u32_to_h2(u))));
        }
    } else {
        uint32_t* __restrict__ yo = packed + ((size_t)(2 * p) * NA + a) * ND;
        #pragma unroll
        for (int i = 0; i < ND; i += 256) {
            float2 v = src[SZ(i + tid)];
            yo[i + tid] = pkrtz_u32(v.x, v.y);
        }
    }
}

// ---------------------------------------------------------------------------
// Kernel 2 (frozen at R11 = best measured, 263us): DMA-staged backprojection
// with lane-masked DMA. At the structural LDS-gather floor: 2 ds_read_b128
// per thread-angle (32B fp16 lerp data / 16B max read width, irreducible),
// 46,080 wave-ops/CU x ~13.7 cyc effective = 263us. Conflicts = 0,
// occupancy 66% (8 blocks/CU; going below hurts — R10), write-port traffic
// non-additive (R11 mask null). Do not touch.
// ---------------------------------------------------------------------------
__global__ __launch_bounds__(256, 8) void backproj_kernel(const uint4* __restrict__ gq,
                                                          const float4* __restrict__ ptable,
                                                          float* __restrict__ img) {
    // win[bank][phase][sg][entry]: 2*4*2*64*16B = 16 KB -> 8 blocks/CU
    __shared__ __align__(16) uint4 win[2][4][2][WREG];

    const int tid = threadIdx.x;
    const int bx = blockIdx.x, by = blockIdx.y, bz = blockIdx.z;

    const float4* __restrict__ pt = ptable + (size_t)((by << 4) + bx) * NA;

    // lane map: wave = 8x x 8y patch; 4 waves tile x
    const int lane = tid & 63;
    const int wid  = tid >> 6;
    const int tx   = (wid << 3) + (lane & 7);
    const int ty   = lane >> 3;                       // 0..7
    const float px  = (float)(bx * TW + tx) - 255.5f;
    const float pyf = (float)(by * TH + ty) - 255.5f;

    // staging sources: quad rows 2bz (sg0: batches 8bz+0..3) and 2bz+1
    // (sg1: batches 8bz+4..7); per-lane global address, linear LDS dest.
    const uint4* __restrict__ q0 = gq + (size_t)(2 * bz) * NA * ND + lane;
    const uint4* __restrict__ q1 = q0 + (size_t)NA * ND;

    float accf[8];
    __half2 hacc01 = u32_to_h2(0u), hacc23 = u32_to_h2(0u),
            hacc45 = u32_to_h2(0u), hacc67 = u32_to_h2(0u);
    #pragma unroll
    for (int b = 0; b < 8; b++) accf[b] = 0.0f;

    auto gld = [](const uint4* g, uint4* l) {
        __builtin_amdgcn_global_load_lds(
            (const __attribute__((address_space(1))) void*)g,
            (__attribute__((address_space(3))) void*)l, 16, 0, 0);
    };
    // stage 4 angles (a..a+3, clamped) into one bank; wave 0, lanes < SLANES
    auto stage4 = [&](int a, uint4* bank) {
        if (lane < SLANES) {
            #pragma unroll
            for (int j = 0; j < 4; j++) {
                const int off = __float_as_int(pt[min(a + j, NA - 1)].w);
                gld(q0 + off, bank + j * (2 * WREG));
                gld(q1 + off, bank + j * (2 * WREG) + WREG);
            }
        }
    };
    auto consume = [&](float4 P, const uint4* wb, int ph) {
        const float t = fmaf(px, P.x, fmaf(pyf, P.y, P.z));
        const int i0 = (int)t;                    // t > 0 -> trunc == floor
#if __has_builtin(__builtin_amdgcn_fractf)
        float w = __builtin_amdgcn_fractf(t);
#else
        float w = t - (float)i0;
#endif
        __half2 wh2 = u32_to_h2(pkrtz_u32(w, w));     // one pkrtz
        const uint4 qA = wb[ph * 2 * WREG + i0];          // ds_read_b128
        const uint4 qB = wb[ph * 2 * WREG + WREG + i0];   // ds_read_b128
        hacc01 = __hfma2(wh2, u32_to_h2(qA.y), __hadd2(hacc01, u32_to_h2(qA.x)));
        hacc23 = __hfma2(wh2, u32_to_h2(qA.w), __hadd2(hacc23, u32_to_h2(qA.z)));
        hacc45 = __hfma2(wh2, u32_to_h2(qB.y), __hadd2(hacc45, u32_to_h2(qB.x)));
        hacc67 = __hfma2(wh2, u32_to_h2(qB.w), __hadd2(hacc67, u32_to_h2(qB.z)));
    };

    // prologue: stage angles 0..3 into bank0; drain; publish
    if (wid == 0) {
        stage4(0, &win[0][0][0][0]);
        asm volatile("s_waitcnt vmcnt(0)" ::: "memory");
    }
    __builtin_amdgcn_s_barrier();

    #pragma unroll 1
    for (int r = 0; r < NA / 4; ++r) {
        const int a = 4 * r;
        const uint4* wb = &win[r & 1][0][0][0];
        if (wid == 0)
            stage4(a + 4, &win[(r + 1) & 1][0][0][0]);
        const float4 P0 = pt[a],     P1 = pt[a + 1];
        const float4 P2 = pt[a + 2], P3 = pt[a + 3];
        consume(P0, wb, 0);
        consume(P1, wb, 1);
        consume(P2, wb, 2);
        consume(P3, wb, 3);

        // flush fp16 group accumulators into fp32 every 4 rounds (16 angles)
        if ((r & 3) == 3) {
            float2 v01 = __half22float2(hacc01);
            float2 v23 = __half22float2(hacc23);
            float2 v45 = __half22float2(hacc45);
            float2 v67 = __half22float2(hacc67);
            accf[0] += v01.x; accf[1] += v01.y;
            accf[2] += v23.x; accf[3] += v23.y;
            accf[4] += v45.x; accf[5] += v45.y;
            accf[6] += v67.x; accf[7] += v67.y;
            hacc01 = u32_to_h2(0u); hacc23 = u32_to_h2(0u);
            hacc45 = u32_to_h2(0u); hacc67 = u32_to_h2(0u);
        }
        if (wid == 0)
            asm volatile("s_waitcnt vmcnt(0)" ::: "memory");
        asm volatile("s_waitcnt lgkmcnt(0)" ::: "memory");
        __builtin_amdgcn_s_barrier();
    }

    const float SCALE = (float)(M_PI / (double)NA);
    const size_t bstride = (size_t)NH * NW;
    size_t o0 = (((size_t)(bz * NBT) * NH) + (by * TH + ty)) * NW + (bx * TW + tx);
    #pragma unroll
    for (int b = 0; b < 8; b++)
        img[o0 + (size_t)b * bstride] = accf[b] * SCALE;
}

// ---------------------------------------------------------------------------
// Fallback backprojection (register staging from packed rows) — used when
// the workspace cannot hold Gq + ptable.
// ---------------------------------------------------------------------------
#define WINN 36
__global__ __launch_bounds__(256, 8) void backproj_fb(const uint32_t* __restrict__ packed,
                                                      const float4* __restrict__ ptable,
                                                      float* __restrict__ img) {
    __shared__ __align__(16) uint4 win[2][8][WINN];

    const int tid = threadIdx.x;
    const int bx = blockIdx.x, by = blockIdx.y, bz = blockIdx.z;

    const float4* __restrict__ pt = ptable + (size_t)((by << 4) + bx) * NA;

    const bool stg = tid < 2 * WINN;
    const int sg   = (tid >= WINN) ? 1 : 0;
    const int si   = tid - sg * WINN;
    const uint32_t* __restrict__ sbA =
        packed + (size_t)(2 * (4 * bz + 2 * sg)) * NA * ND + si;
    const uint32_t* __restrict__ sbB = sbA + (size_t)2 * NA * ND;
    uint4* const wptr = &win[sg][0][si];

    const int lane = tid & 63;
    const int wid  = tid >> 6;
    const int tx   = (wid << 3) + (lane & 7);
    const int ty   = lane >> 3;
    const float px  = (float)(bx * TW + tx) - 255.5f;
    const float pyf = (float)(by * TH + ty) - 255.5f;

    float accf[8];
    __half2 hacc01 = u32_to_h2(0u), hacc23 = u32_to_h2(0u),
            hacc45 = u32_to_h2(0u), hacc67 = u32_to_h2(0u);
    #pragma unroll
    for (int b = 0; b < 8; b++) accf[b] = 0.0f;

    auto bar = []() {
        asm volatile("s_waitcnt lgkmcnt(0)" ::: "memory");
        __builtin_amdgcn_s_barrier();
    };
    auto stage_load = [&](float4 P, uint2& wA, uint2& wB) {
        const int off = __float_as_int(P.w);
        wA = make_uint2(sbA[off], sbA[off + 1]);
        wB = make_uint2(sbB[off], sbB[off + 1]);
    };
    auto stage_write = [&](int ph, uint2 wA, uint2 wB) {
        wptr[ph * WINN] = make_uint4(
            wA.x, h2_to_u32(__hsub2(u32_to_h2(wA.y), u32_to_h2(wA.x))),
            wB.x, h2_to_u32(__hsub2(u32_to_h2(wB.y), u32_to_h2(wB.x))));
    };
    auto consume = [&](float4 P, int ph) {
        const float t = fmaf(px, P.x, fmaf(pyf, P.y, P.z));
        const int i0 = (int)t;
#if __has_builtin(__builtin_amdgcn_fractf)
        float w = __builtin_amdgcn_fractf(t);
#else
        float w = t - (float)i0;
#endif
        __half2 wh2 = u32_to_h2(pkrtz_u32(w, w));
        const uint4 qA = win[0][ph][i0];
        const uint4 qB = win[1][ph][i0];
        hacc01 = __hfma2(wh2, u32_to_h2(qA.y), __hadd2(hacc01, u32_to_h2(qA.x)));
        hacc23 = __hfma2(wh2, u32_to_h2(qA.w), __hadd2(hacc23, u32_to_h2(qA.z)));
        hacc45 = __hfma2(wh2, u32_to_h2(qB.y), __hadd2(hacc45, u32_to_h2(qB.x)));
        hacc67 = __hfma2(wh2, u32_to_h2(qB.w), __hadd2(hacc67, u32_to_h2(qB.z)));
    };

    uint2 h0A = make_uint2(0, 0), h0B = make_uint2(0, 0);
    uint2 h1A = make_uint2(0, 0), h1B = make_uint2(0, 0);
    uint2 h2A = make_uint2(0, 0), h2B = make_uint2(0, 0);
    uint2 h3A = make_uint2(0, 0), h3B = make_uint2(0, 0);

    if (stg) {
        uint2 wA, wB;
        stage_load(pt[0], wA, wB);  stage_write(0, wA, wB);
        stage_load(pt[1], wA, wB);  stage_write(1, wA, wB);
        stage_load(pt[2], wA, wB);  stage_write(2, wA, wB);
        stage_load(pt[3], wA, wB);  stage_write(3, wA, wB);
        stage_load(pt[4], h0A, h0B);
        stage_load(pt[5], h1A, h1B);
        stage_load(pt[6], h2A, h2B);
        stage_load(pt[7], h3A, h3B);
    }
    bar();

    #pragma unroll 1
    for (int r = 0; r < NA / 4; ++r) {
        const int a = 4 * r;
        const int cb = (r & 1) * 4;
        const int ob = cb ^ 4;
        const float4 P0 = pt[a],     P1 = pt[a + 1];
        const float4 P2 = pt[a + 2], P3 = pt[a + 3];

        if (stg) {
            stage_write(ob + 0, h0A, h0B);
            stage_write(ob + 1, h1A, h1B);
            stage_write(ob + 2, h2A, h2B);
            stage_write(ob + 3, h3A, h3B);
            stage_load(pt[min(a + 8,  NA - 1)], h0A, h0B);
            stage_load(pt[min(a + 9,  NA - 1)], h1A, h1B);
            stage_load(pt[min(a + 10, NA - 1)], h2A, h2B);
            stage_load(pt[min(a + 11, NA - 1)], h3A, h3B);
        }
        consume(P0, cb + 0);
        consume(P1, cb + 1);
        consume(P2, cb + 2);
        consume(P3, cb + 3);

        if ((r & 3) == 3) {
            float2 v01 = __half22float2(hacc01);
            float2 v23 = __half22float2(hacc23);
            float2 v45 = __half22float2(hacc45);
            float2 v67 = __half22float2(hacc67);
            accf[0] += v01.x; accf[1] += v01.y;
            accf[2] += v23.x; accf[3] += v23.y;
            accf[4] += v45.x; accf[5] += v45.y;
            accf[6] += v67.x; accf[7] += v67.y;
            hacc01 = u32_to_h2(0u); hacc23 = u32_to_h2(0u);
            hacc45 = u32_to_h2(0u); hacc67 = u32_to_h2(0u);
        }
        bar();
    }

    const float SCALE = (float)(M_PI / (double)NA);
    const size_t bstride = (size_t)NH * NW;
    size_t o0 = (((size_t)(bz * NBT) * NH) + (by * TH + ty)) * NW + (bx * TW + tx);
    #pragma unroll
    for (int b = 0; b < 8; b++)
        img[o0 + (size_t)b * bstride] = accf[b] * SCALE;
}

// ---------------------------------------------------------------------------
extern "C" void kernel_launch(void* const* d_in, const int* in_sizes, int n_in,
                              void* d_out, int out_size, void* d_ws, size_t ws_size,
                              hipStream_t stream) {
    const float* sino = (const float*)d_in[0];
    const float* filt = (const float*)d_in[1];
    float* out = (float*)d_out;

    const size_t gq_bytes   = (size_t)4 * NA * ND * sizeof(uint4);       // 47.2 MB
    const size_t ptab_bytes = (size_t)1024 * NA * sizeof(float4);        // 11.8 MB
    const size_t twg_bytes  = (size_t)768 * sizeof(float2);              //  6 KB

    if (ws_size >= gq_bytes + ptab_bytes + twg_bytes) {
        uint4*  gq     = (uint4*)d_ws;
        float4* ptable = (float4*)((char*)d_ws + gq_bytes);
        float2* twg    = (float2*)((char*)d_ws + gq_bytes + ptab_bytes);
        prep_kernel<<<dim3(1025), dim3(768), 0, stream>>>(ptable, twg);
        filter_kernel<<<dim3(NA, NB / 2), dim3(256), 0, stream>>>(sino, filt, twg, gq, nullptr);
        backproj_kernel<<<dim3(NW / TW, NH / TH, NB / NBT), dim3(256), 0, stream>>>(gq, ptable, out);
    } else {
        // fallback: pack fp16 rows in-place into the input (block-local
        // writes); ptable + twiddles in d_ws; register-staging backproj.
        uint32_t* packed = (uint32_t*)d_in[0];
        float4* ptable   = (float4*)d_ws;
        float2* twg      = (float2*)((char*)d_ws + ptab_bytes);
        prep_kernel<<<dim3(1025), dim3(768), 0, stream>>>(ptable, twg);
        filter_kernel<<<dim3(NA, NB / 2), dim3(256), 0, stream>>>(sino, filt, twg, nullptr, packed);
        backproj_fb<<<dim3(NW / TW, NH / TH, NB / NBT), dim3(256), 0, stream>>>(packed, ptable, out);
    }
}